// Round 1
// baseline (867.525 us; speedup 1.0000x reference)
//
#include <hip/hip_runtime.h>
#include <hip/hip_bf16.h>

#define BB 512
#define SS 50
#define HH 20
#define NN 100000
#define MC 128   // m-chunk size for attention partials

// ---------------- workspace layout (floats) ----------------
// item_h  [B][S][H]      0
// cat_h   [B][S][H]      512000
// hin     [B][S][H]      1024000
// hout    [B][S][H]      1536000
// q_t     [S][B][H]      2048000
// k_t     [S][B][H]      2560000
// v_t     [S][B][H]      3072000
// pbuf    [S][4][B][24]  3584000   (50*4*512*24 = 2457600)
// ht_item [B][H]         6041600
// ht_cat  [B][H]         6051840
// final   [B][H]         6062080
// last    [B] (int)      6072320

__global__ __launch_bounds__(256)
void k_gather(const int* __restrict__ inputs, const int* __restrict__ category,
              const float* __restrict__ emb, const float* __restrict__ emb1,
              const float* __restrict__ w_ein, const float* __restrict__ b_ein,
              const float* __restrict__ w_eout, const float* __restrict__ b_eout,
              float* __restrict__ item_h, float* __restrict__ cat_h,
              float* __restrict__ hin, float* __restrict__ hout) {
    __shared__ float swin[HH*HH], swout[HH*HH], sbin[HH], sbout[HH];
    int t = threadIdx.x;
    for (int i = t; i < HH*HH; i += 256) { swin[i] = w_ein[i]; swout[i] = w_eout[i]; }
    if (t < HH) { sbin[t] = b_ein[t]; sbout[t] = b_eout[t]; }
    __syncthreads();
    int idx = blockIdx.x * 256 + t;
    if (idx >= BB*SS) return;
    float h[HH];
    const float* er = emb + (size_t)inputs[idx] * HH;
    #pragma unroll
    for (int e = 0; e < HH; e++) { h[e] = er[e]; item_h[(size_t)idx*HH + e] = h[e]; }
    const float* cr = emb1 + (size_t)category[idx] * HH;
    #pragma unroll
    for (int e = 0; e < HH; e++) cat_h[(size_t)idx*HH + e] = cr[e];
    for (int c = 0; c < HH; c++) {
        float si = sbin[c], so = sbout[c];
        #pragma unroll
        for (int e = 0; e < HH; e++) { si += swin[c*HH+e]*h[e]; so += swout[c*HH+e]*h[e]; }
        hin[(size_t)idx*HH + c] = si;
        hout[(size_t)idx*HH + c] = so;
    }
}

__global__ __launch_bounds__(256)
void k_gnn(const float* __restrict__ A, const float* __restrict__ hin,
           const float* __restrict__ hout,
           const float* __restrict__ b_iah, const float* __restrict__ b_oah,
           const float* __restrict__ w_ih, const float* __restrict__ b_ih,
           const float* __restrict__ w_hh, const float* __restrict__ b_hh,
           float* __restrict__ h) {
    __shared__ float sA[SS*2*SS];
    __shared__ float shin[SS*HH], shout[SS*HH], sh[SS*HH];
    __shared__ float sin_[SS*HH], sout_[SS*HH];
    __shared__ float swih[60*40], swhh[60*20];
    __shared__ float sbih[60], sbhh[60], sbiah[HH], sboah[HH];
    int b = blockIdx.x, t = threadIdx.x;
    for (int i = t; i < SS*2*SS; i += 256) sA[i] = A[(size_t)b*SS*2*SS + i];
    for (int i = t; i < SS*HH; i += 256) {
        shin[i]  = hin [(size_t)b*SS*HH + i];
        shout[i] = hout[(size_t)b*SS*HH + i];
        sh[i]    = h   [(size_t)b*SS*HH + i];
    }
    for (int i = t; i < 60*40; i += 256) swih[i] = w_ih[i];
    for (int i = t; i < 60*20; i += 256) swhh[i] = w_hh[i];
    if (t < 60) { sbih[t] = b_ih[t]; sbhh[t] = b_hh[t]; }
    if (t < HH) { sbiah[t] = b_iah[t]; sboah[t] = b_oah[t]; }
    __syncthreads();
    for (int ie = t; ie < SS*HH; ie += 256) {
        int i = ie / HH, e = ie % HH;
        float ai = sbiah[e], ao = sboah[e];
        for (int j = 0; j < SS; j++) {
            ai += sA[i*2*SS + j]      * shin[j*HH + e];
            ao += sA[i*2*SS + SS + j] * shout[j*HH + e];
        }
        sin_[ie] = ai; sout_[ie] = ao;
    }
    __syncthreads();
    for (int ie = t; ie < SS*HH; ie += 256) {
        int i = ie / HH, e = ie % HH;
        float gir = sbih[e], gii = sbih[20+e], gin = sbih[40+e];
        #pragma unroll
        for (int k = 0; k < HH; k++) {
            float vi = sin_[i*HH+k], vo = sout_[i*HH+k];
            gir += swih[e*40+k]*vi      + swih[e*40+20+k]*vo;
            gii += swih[(20+e)*40+k]*vi + swih[(20+e)*40+20+k]*vo;
            gin += swih[(40+e)*40+k]*vi + swih[(40+e)*40+20+k]*vo;
        }
        float ghr = sbhh[e], ghi = sbhh[20+e], ghn = sbhh[40+e];
        #pragma unroll
        for (int k = 0; k < HH; k++) {
            float hv = sh[i*HH+k];
            ghr += swhh[e*20+k]*hv; ghi += swhh[(20+e)*20+k]*hv; ghn += swhh[(40+e)*20+k]*hv;
        }
        float r = 1.f/(1.f+expf(-(gir+ghr)));
        float z = 1.f/(1.f+expf(-(gii+ghi)));
        float n = tanhf(gin + r*ghn);
        float hv = sh[ie];
        h[(size_t)b*SS*HH + ie] = n + z*(hv - n);
    }
}

__global__ __launch_bounds__(64)
void k_last(const int* __restrict__ mask, const float* __restrict__ item_h,
            const float* __restrict__ cat_h,
            int* __restrict__ last, float* __restrict__ ht_item, float* __restrict__ ht_cat) {
    int b = blockIdx.x * 64 + threadIdx.x;
    if (b >= BB) return;
    int s = 0;
    for (int i = 0; i < SS; i++) s += mask[b*SS + i];
    int l = s - 1;
    last[b] = l;
    for (int e = 0; e < HH; e++) {
        ht_item[b*HH+e] = item_h[((size_t)b*SS + l)*HH + e];
        ht_cat [b*HH+e] = cat_h [((size_t)b*SS + l)*HH + e];
    }
}

__global__ __launch_bounds__(256)
void k_qkv(const float* __restrict__ x, const float* __restrict__ in_w,
           const float* __restrict__ in_b,
           float* __restrict__ q_t, float* __restrict__ k_t, float* __restrict__ v_t) {
    __shared__ float sw[60*HH], sb[60];
    int t = threadIdx.x;
    for (int i = t; i < 60*HH; i += 256) sw[i] = in_w[i];
    if (t < 60) sb[t] = in_b[t];
    __syncthreads();
    int idx = blockIdx.x * 256 + t;
    if (idx >= BB*SS) return;
    int b = idx / SS, s = idx % SS;
    float xr[HH];
    #pragma unroll
    for (int e = 0; e < HH; e++) xr[e] = x[(size_t)idx*HH + e];
    const float scale = 0.22360679774997896f;  // 1/sqrt(20)
    for (int c = 0; c < HH; c++) {
        float acc = sb[c];
        #pragma unroll
        for (int e = 0; e < HH; e++) acc += sw[c*HH+e]*xr[e];
        q_t[((size_t)s*BB + b)*HH + c] = acc * scale;
    }
    for (int c = 0; c < HH; c++) {
        float acc = sb[20+c];
        #pragma unroll
        for (int e = 0; e < HH; e++) acc += sw[(20+c)*HH+e]*xr[e];
        k_t[((size_t)s*BB + b)*HH + c] = acc;
    }
    for (int c = 0; c < HH; c++) {
        float acc = sb[40+c];
        #pragma unroll
        for (int e = 0; e < HH; e++) acc += sw[(40+c)*HH+e]*xr[e];
        v_t[((size_t)s*BB + b)*HH + c] = acc;
    }
}

__global__ __launch_bounds__(256)
void k_attn_part(const float* __restrict__ q_t, const float* __restrict__ k_t,
                 const float* __restrict__ v_t, float* __restrict__ pbuf) {
    __shared__ float sk[MC*HH], sv[MC*HH];
    int n = blockIdx.x, lt = blockIdx.y, mc = blockIdx.z, t = threadIdx.x;
    const float* kb = k_t + ((size_t)n*BB + mc*MC)*HH;
    const float* vb = v_t + ((size_t)n*BB + mc*MC)*HH;
    for (int i = t; i < MC*HH; i += 256) { sk[i] = kb[i]; sv[i] = vb[i]; }
    __syncthreads();
    int l = lt*256 + t;
    float q[HH];
    #pragma unroll
    for (int e = 0; e < HH; e++) q[e] = q_t[((size_t)n*BB + l)*HH + e];
    float mx = -1e30f, sum = 0.f, o[HH];
    #pragma unroll
    for (int e = 0; e < HH; e++) o[e] = 0.f;
    for (int m = 0; m < MC; m++) {
        float s = 0.f;
        #pragma unroll
        for (int e = 0; e < HH; e++) s += q[e]*sk[m*HH+e];
        float nm = fmaxf(mx, s);
        float c = expf(mx - nm);
        float p = expf(s - nm);
        sum = sum*c + p;
        #pragma unroll
        for (int e = 0; e < HH; e++) o[e] = o[e]*c + p*sv[m*HH+e];
        mx = nm;
    }
    float* pb = pbuf + (((size_t)n*4 + mc)*BB + l)*24;
    pb[0] = mx; pb[1] = sum;
    #pragma unroll
    for (int e = 0; e < HH; e++) pb[2+e] = o[e];
}

__global__ __launch_bounds__(256)
void k_attn_fin(const float* __restrict__ pbuf, const float* __restrict__ out_w,
                const float* __restrict__ out_b,
                const float* __restrict__ w1, const float* __restrict__ b1,
                const float* __restrict__ w2, const float* __restrict__ b2,
                float* __restrict__ x) {
    __shared__ float sow[HH*HH], sw1[HH*HH], sw2[HH*HH], sob[HH], sb1[HH], sb2[HH];
    int t = threadIdx.x;
    for (int i = t; i < HH*HH; i += 256) { sow[i] = out_w[i]; sw1[i] = w1[i]; sw2[i] = w2[i]; }
    if (t < HH) { sob[t] = out_b[t]; sb1[t] = b1[t]; sb2[t] = b2[t]; }
    __syncthreads();
    int idx = blockIdx.x*256 + t;
    if (idx >= BB*SS) return;
    int b = idx / SS, s = idx % SS;
    const float* p0 = pbuf + ((size_t)s*4*BB + b)*24;
    float mx = -1e30f;
    #pragma unroll
    for (int mc = 0; mc < 4; mc++) mx = fmaxf(mx, p0[(size_t)mc*BB*24]);
    float sum = 0.f, o[HH];
    #pragma unroll
    for (int e = 0; e < HH; e++) o[e] = 0.f;
    #pragma unroll
    for (int mc = 0; mc < 4; mc++) {
        const float* p = p0 + (size_t)mc*BB*24;
        float c = expf(p[0] - mx);
        sum += p[1]*c;
        #pragma unroll
        for (int e = 0; e < HH; e++) o[e] += p[2+e]*c;
    }
    float inv = 1.f/sum;
    float ao[HH];
    #pragma unroll
    for (int e = 0; e < HH; e++) ao[e] = o[e]*inv;
    float mo[HH];
    for (int e = 0; e < HH; e++) {
        float a = sob[e];
        #pragma unroll
        for (int f = 0; f < HH; f++) a += sow[e*HH+f]*ao[f];
        mo[e] = a;
    }
    float u[HH];
    for (int g = 0; g < HH; g++) {
        float a = sb1[g];
        #pragma unroll
        for (int f = 0; f < HH; f++) a += sw1[g*HH+f]*mo[f];
        u[g] = fmaxf(a, 0.f);
    }
    for (int e = 0; e < HH; e++) {
        float a = mo[e] + sb2[e];
        #pragma unroll
        for (int g = 0; g < HH; g++) a += sw2[e*HH+g]*u[g];
        x[(size_t)idx*HH + e] = a;
    }
}

__global__ __launch_bounds__(256)
void k_head(const float* __restrict__ x, const float* __restrict__ y,
            const int* __restrict__ last,
            const float* __restrict__ ht_item, const float* __restrict__ ht_cat,
            const float* __restrict__ mem_M, const float* __restrict__ mem_Wa,
            const float* __restrict__ mem_fc,
            const float* __restrict__ wc, const float* __restrict__ bc,
            const float* __restrict__ wp, const float* __restrict__ bp,
            float* __restrict__ final_) {
    int b = blockIdx.x*256 + threadIdx.x;
    if (b >= BB) return;
    int l = last[b];
    float a[40];
    for (int e = 0; e < HH; e++)
        a[e]    = 0.52f*x[((size_t)b*SS + l)*HH + e] + 0.48f*ht_item[b*HH+e];
    for (int e = 0; e < HH; e++)
        a[20+e] = 0.52f*y[((size_t)b*SS + l)*HH + e] + 0.48f*ht_cat[b*HH+e];
    float t20[20];
    for (int j = 0; j < 20; j++) {
        float acc = 0.f;
        for (int k = 0; k < 40; k++) acc += a[k]*mem_Wa[k*20+j];
        t20[j] = acc;
    }
    float lg[10]; float mxv = -1e30f;
    for (int c = 0; c < 10; c++) {
        float acc = 0.f;
        for (int j = 0; j < 20; j++) acc += t20[j]*mem_M[c*20+j];
        lg[c] = acc; mxv = fmaxf(mxv, acc);
    }
    float se = 0.f;
    for (int c = 0; c < 10; c++) { lg[c] = expf(lg[c]-mxv); se += lg[c]; }
    float inv = 1.f/se;
    for (int c = 0; c < 10; c++) lg[c] *= inv;
    float am[20];
    for (int j = 0; j < 20; j++) {
        float acc = 0.f;
        for (int c = 0; c < 10; c++) acc += lg[c]*mem_M[c*20+j];
        am[j] = acc;
    }
    float reps[20];
    for (int j2 = 0; j2 < 20; j2++) {
        float acc = 0.f;
        for (int j = 0; j < 20; j++) acc += am[j]*mem_fc[j*20+j2];
        reps[j2] = tanhf(acc);
    }
    for (int e = 0; e < HH; e++) {
        float c1 = bc[e], c2 = bp[e];
        for (int k = 0; k < 40; k++) { c1 += a[k]*wc[e*60+k]; c2 += a[k]*wp[e*60+k]; }
        for (int k = 0; k < 20; k++) { c1 += reps[k]*wc[e*60+40+k]; c2 += reps[k]*wp[e*60+40+k]; }
        c1 = 1.f/(1.f+expf(-c1));
        final_[b*HH+e] = c1*c2;
    }
}

__global__ __launch_bounds__(256)
void k_scores(const float* __restrict__ final_, const float* __restrict__ emb,
              float* __restrict__ out) {
    int node = blockIdx.x*256 + threadIdx.x;
    if (node >= NN-1) return;
    float er[HH];
    const float4* e4 = (const float4*)(emb + ((size_t)node + 1)*HH);
    float4 a0 = e4[0], a1 = e4[1], a2 = e4[2], a3 = e4[3], a4 = e4[4];
    er[0]=a0.x; er[1]=a0.y; er[2]=a0.z; er[3]=a0.w;
    er[4]=a1.x; er[5]=a1.y; er[6]=a1.z; er[7]=a1.w;
    er[8]=a2.x; er[9]=a2.y; er[10]=a2.z; er[11]=a2.w;
    er[12]=a3.x; er[13]=a3.y; er[14]=a3.z; er[15]=a3.w;
    er[16]=a4.x; er[17]=a4.y; er[18]=a4.z; er[19]=a4.w;
    float* op = out + node;
    for (int b = 0; b < BB; b++) {
        const float* fb = final_ + b*HH;
        float acc = 0.f;
        #pragma unroll
        for (int e = 0; e < HH; e++) acc += fb[e]*er[e];
        *op = acc;
        op += (NN-1);
    }
}

extern "C" void kernel_launch(void* const* d_in, const int* in_sizes, int n_in,
                              void* d_out, int out_size, void* d_ws, size_t ws_size,
                              hipStream_t stream) {
    const int*   inputs   = (const int*)  d_in[0];
    const int*   category = (const int*)  d_in[1];
    const float* A        = (const float*)d_in[2];
    const int*   mask     = (const int*)  d_in[3];
    const float* emb      = (const float*)d_in[4];
    const float* emb1     = (const float*)d_in[5];
    const float* w_ih     = (const float*)d_in[6];
    const float* w_hh     = (const float*)d_in[7];
    const float* b_ih     = (const float*)d_in[8];
    const float* b_hh     = (const float*)d_in[9];
    const float* b_iah    = (const float*)d_in[10];
    const float* b_oah    = (const float*)d_in[11];
    const float* w_ein    = (const float*)d_in[12];
    const float* b_ein    = (const float*)d_in[13];
    const float* w_eout   = (const float*)d_in[14];
    const float* b_eout   = (const float*)d_in[15];
    const float* mha_in_w  = (const float*)d_in[16];
    const float* mha_in_b  = (const float*)d_in[17];
    const float* mha_out_w = (const float*)d_in[18];
    const float* mha_out_b = (const float*)d_in[19];
    const float* mha1_in_w  = (const float*)d_in[20];
    const float* mha1_in_b  = (const float*)d_in[21];
    const float* mha1_out_w = (const float*)d_in[22];
    const float* mha1_out_b = (const float*)d_in[23];
    const float* rn_w1 = (const float*)d_in[24];
    const float* rn_b1 = (const float*)d_in[25];
    const float* rn_w2 = (const float*)d_in[26];
    const float* rn_b2 = (const float*)d_in[27];
    const float* rn1_w1 = (const float*)d_in[28];
    const float* rn1_b1 = (const float*)d_in[29];
    const float* rn1_w2 = (const float*)d_in[30];
    const float* rn1_b2 = (const float*)d_in[31];
    const float* mem_M  = (const float*)d_in[32];
    const float* mem_Wa = (const float*)d_in[33];
    const float* mem_fc = (const float*)d_in[34];
    const float* wc = (const float*)d_in[35];
    const float* bc = (const float*)d_in[36];
    const float* wp = (const float*)d_in[37];
    const float* bp = (const float*)d_in[38];
    float* out = (float*)d_out;

    float* W = (float*)d_ws;
    float* item_h = W;
    float* cat_h  = W + 512000;
    float* hin    = W + 1024000;
    float* hout   = W + 1536000;
    float* q_t    = W + 2048000;
    float* k_t    = W + 2560000;
    float* v_t    = W + 3072000;
    float* pbuf   = W + 3584000;
    float* ht_item = W + 6041600;
    float* ht_cat  = W + 6051840;
    float* final_  = W + 6062080;
    int*   last    = (int*)(W + 6072320);

    // 1. gather + edge projections
    k_gather<<<100, 256, 0, stream>>>(inputs, category, emb, emb1,
                                      w_ein, b_ein, w_eout, b_eout,
                                      item_h, cat_h, hin, hout);
    // 2. GNN cell (STEP=1), in-place on item_h
    k_gnn<<<BB, 256, 0, stream>>>(A, hin, hout, b_iah, b_oah,
                                  w_ih, b_ih, w_hh, b_hh, item_h);
    // 3. last index + ht snapshots
    k_last<<<8, 64, 0, stream>>>(mask, item_h, cat_h, last, ht_item, ht_cat);

    // 4. item path: 2 x (MHA + residual), in-place on item_h
    for (int kb = 0; kb < 2; kb++) {
        k_qkv<<<100, 256, 0, stream>>>(item_h, mha_in_w, mha_in_b, q_t, k_t, v_t);
        k_attn_part<<<dim3(SS, 2, 4), 256, 0, stream>>>(q_t, k_t, v_t, pbuf);
        k_attn_fin<<<100, 256, 0, stream>>>(pbuf, mha_out_w, mha_out_b,
                                            rn_w1, rn_b1, rn_w2, rn_b2, item_h);
    }
    // 5. cat path
    for (int kb = 0; kb < 2; kb++) {
        k_qkv<<<100, 256, 0, stream>>>(cat_h, mha1_in_w, mha1_in_b, q_t, k_t, v_t);
        k_attn_part<<<dim3(SS, 2, 4), 256, 0, stream>>>(q_t, k_t, v_t, pbuf);
        k_attn_fin<<<100, 256, 0, stream>>>(pbuf, mha1_out_w, mha1_out_b,
                                            rn1_w1, rn1_b1, rn1_w2, rn1_b2, cat_h);
    }
    // 6. memory readout + heads -> final [B,H]
    k_head<<<2, 256, 0, stream>>>(item_h, cat_h, last, ht_item, ht_cat,
                                  mem_M, mem_Wa, mem_fc, wc, bc, wp, bp, final_);
    // 7. scores = final @ emb[1:].T
    k_scores<<<(NN-1+255)/256, 256, 0, stream>>>(final_, emb, out);
}

// Round 2
// 656.062 us; speedup vs baseline: 1.3223x; 1.3223x over previous
//
#include <hip/hip_runtime.h>
#include <hip/hip_bf16.h>

#define BB 512
#define SS 50
#define HH 20
#define NN 100000
#define MC 128          // m-chunk per attention block
#define MT 16           // m tile cached in registers
#define PBSTRIDE ((size_t)BB*24)

__device__ __forceinline__ float frcp(float x){
#if __has_builtin(__builtin_amdgcn_rcpf)
  return __builtin_amdgcn_rcpf(x);
#else
  return 1.f/x;
#endif
}
__device__ __forceinline__ float fsig(float x){ return frcp(1.f + __expf(-x)); }
__device__ __forceinline__ float ftanh(float x){ return 1.f - 2.f*frcp(1.f + __expf(2.f*x)); }

// ------------------------------------------------------------------
// Fused: embedding gather + edge proj + GNN cell + last/ht snapshot +
// layer-1 QKV for BOTH paths. One block per session b.
// ------------------------------------------------------------------
__global__ __launch_bounds__(256)
void k_gnnqkv(const int* __restrict__ inputs, const int* __restrict__ category,
              const float* __restrict__ A, const int* __restrict__ mask,
              const float* __restrict__ emb, const float* __restrict__ emb1,
              const float* __restrict__ w_ih, const float* __restrict__ w_hh,
              const float* __restrict__ b_ih, const float* __restrict__ b_hh,
              const float* __restrict__ b_iah, const float* __restrict__ b_oah,
              const float* __restrict__ w_ein, const float* __restrict__ b_ein,
              const float* __restrict__ w_eout, const float* __restrict__ b_eout,
              const float* __restrict__ inw0, const float* __restrict__ inb0,
              const float* __restrict__ inw1, const float* __restrict__ inb1,
              float* __restrict__ q_t, float* __restrict__ k_t, float* __restrict__ v_t,
              int* __restrict__ last, float* __restrict__ ht_item, float* __restrict__ ht_cat)
{
    __shared__ float sA[SS*2*SS];
    __shared__ float sit[SS*HH], sct[SS*HH], shin[SS*HH], shout[SS*HH];
    __shared__ float sinp[SS*HH], soutp[SS*HH];
    __shared__ float swein[HH*HH], sweout[HH*HH];
    __shared__ float swih[60*40], swhh[60*HH];
    __shared__ float sw0[60*HH], sw1w[60*HH];
    __shared__ float sbein[HH], sbeout[HH], sbih[60], sbhh[60], sbiah[HH], sboah[HH], sb0[60], sb1b[60];
    __shared__ int slast;
    const int b = blockIdx.x, t = threadIdx.x;

    for (int i=t;i<SS*2*SS;i+=256) sA[i] = A[(size_t)b*SS*2*SS + i];
    for (int i=t;i<HH*HH;i+=256) { swein[i]=w_ein[i]; sweout[i]=w_eout[i]; }
    for (int i=t;i<60*40;i+=256) swih[i]=w_ih[i];
    for (int i=t;i<60*HH;i+=256) { swhh[i]=w_hh[i]; sw0[i]=inw0[i]; sw1w[i]=inw1[i]; }
    if (t<60){ sbih[t]=b_ih[t]; sbhh[t]=b_hh[t]; sb0[t]=inb0[t]; sb1b[t]=inb1[t]; }
    if (t<HH){ sbein[t]=b_ein[t]; sbeout[t]=b_eout[t]; sbiah[t]=b_iah[t]; sboah[t]=b_oah[t]; }
    for (int i=t;i<SS*HH;i+=256){
        int r=i/HH, e=i%HH;
        sit[i]=emb [(size_t)inputs  [b*SS+r]*HH+e];
        sct[i]=emb1[(size_t)category[b*SS+r]*HH+e];
    }
    if (t==0){ int s=0; for (int j=0;j<SS;j++) s+=mask[b*SS+j]; slast=s-1; }
    __syncthreads();

    // hin/hout = h @ w_ein.T + b ; h @ w_eout.T + b
    for (int i=t;i<SS*HH;i+=256){
        int r=i/HH, c=i%HH;
        float si=sbein[c], so=sbeout[c];
        #pragma unroll
        for (int e=0;e<HH;e++){ float hv=sit[r*HH+e]; si+=swein[c*HH+e]*hv; so+=sweout[c*HH+e]*hv; }
        shin[i]=si; shout[i]=so;
    }
    __syncthreads();
    // A-propagation
    for (int i=t;i<SS*HH;i+=256){
        int r=i/HH, e=i%HH;
        float ai=sbiah[e], ao=sboah[e];
        for (int j=0;j<SS;j++){
            ai+=sA[r*2*SS+j]   *shin [j*HH+e];
            ao+=sA[r*2*SS+SS+j]*shout[j*HH+e];
        }
        sinp[i]=ai; soutp[i]=ao;
    }
    __syncthreads();
    // GRU gates
    float nh[4];
    #pragma unroll
    for (int ii=0;ii<4;ii++){
        int i=t+ii*256;
        if (i<SS*HH){
            int r=i/HH, e=i%HH;
            float gir=sbih[e], gii=sbih[20+e], gin=sbih[40+e];
            #pragma unroll
            for (int k=0;k<HH;k++){
                float vi=sinp[r*HH+k], vo=soutp[r*HH+k];
                gir+=swih[e*40+k]*vi      + swih[e*40+HH+k]*vo;
                gii+=swih[(20+e)*40+k]*vi + swih[(20+e)*40+HH+k]*vo;
                gin+=swih[(40+e)*40+k]*vi + swih[(40+e)*40+HH+k]*vo;
            }
            float ghr=sbhh[e], ghi=sbhh[20+e], ghn=sbhh[40+e];
            #pragma unroll
            for (int k=0;k<HH;k++){
                float hv=sit[r*HH+k];
                ghr+=swhh[e*HH+k]*hv; ghi+=swhh[(20+e)*HH+k]*hv; ghn+=swhh[(40+e)*HH+k]*hv;
            }
            float rr=fsig(gir+ghr), zz=fsig(gii+ghi);
            float nn2=ftanh(gin+rr*ghn);
            nh[ii]=nn2+zz*(sit[i]-nn2);
        }
    }
    __syncthreads();
    #pragma unroll
    for (int ii=0;ii<4;ii++){ int i=t+ii*256; if (i<SS*HH) sit[i]=nh[ii]; }
    __syncthreads();

    // ht snapshots + last
    if (t<HH)                    ht_item[b*HH+t]      = sit[slast*HH+t];
    else if (t>=32 && t<32+HH)   ht_cat [b*HH+(t-32)] = sct[slast*HH+(t-32)];
    else if (t==63)              last[b]=slast;

    // layer-1 QKV for both paths
    const float SCALE = 0.22360679774997896f;
    for (int oi=t; oi<2*SS*60; oi+=256){
        int p=oi/(SS*60); int rem=oi%(SS*60); int r=rem/60; int c=rem%60;
        const float* src = p? sct  : sit;
        const float* w   = p? sw1w : sw0;
        const float* bb_ = p? sb1b : sb0;
        float acc=bb_[c];
        #pragma unroll
        for (int e=0;e<HH;e++) acc += w[c*HH+e]*src[r*HH+e];
        int which=c/HH, cc=c%HH;
        size_t off=((size_t)(p*SS+r)*BB + b)*HH + cc;
        if (which==0)      q_t[off]=acc*SCALE;
        else if (which==1) k_t[off]=acc;
        else               v_t[off]=acc;
    }
}

// ------------------------------------------------------------------
// Attention partials: flash-style over the 512-long axis. 2 rows/thread,
// 16-m register tiles, deferred rescale, b128 LDS reads, fast exp.
// grid (n=50, path=2, mc=4)
// ------------------------------------------------------------------
__global__ __launch_bounds__(256)
void k_attn(const float* __restrict__ q_t, const float* __restrict__ k_t,
            const float* __restrict__ v_t, float* __restrict__ pbuf)
{
    __shared__ float sk[MC*HH], sv[MC*HH];
    const int n=blockIdx.x, p=blockIdx.y, mc=blockIdx.z, t=threadIdx.x;
    const size_t base=(size_t)(p*SS+n)*BB;
    {
        const float4* kb=(const float4*)(k_t+(base+(size_t)mc*MC)*HH);
        const float4* vb=(const float4*)(v_t+(base+(size_t)mc*MC)*HH);
        float4* sk4=(float4*)sk; float4* sv4=(float4*)sv;
        for (int i=t;i<MC*HH/4;i+=256){ sk4[i]=kb[i]; sv4[i]=vb[i]; }
    }
    __syncthreads();
    float4 q0[5], q1[5];
    {
        const float4* qp0=(const float4*)(q_t+(base+t)*HH);
        const float4* qp1=(const float4*)(q_t+(base+t+256)*HH);
        #pragma unroll
        for (int i=0;i<5;i++){ q0[i]=qp0[i]; q1[i]=qp1[i]; }
    }
    float4 o0[5], o1[5];
    #pragma unroll
    for (int i=0;i<5;i++){ o0[i]=make_float4(0.f,0.f,0.f,0.f); o1[i]=make_float4(0.f,0.f,0.f,0.f); }
    float mx0=-1e30f, mx1=-1e30f, sm0=0.f, sm1=0.f;

    for (int mt0=0; mt0<MC; mt0+=MT){
        float s0[MT], s1[MT];
        float tm0=-1e30f, tm1=-1e30f;
        #pragma unroll
        for (int j=0;j<MT;j++){
            const float4* kr=(const float4*)(sk+(mt0+j)*HH);
            float a0=0.f, a1=0.f;
            #pragma unroll
            for (int i=0;i<5;i++){
                float4 kv=kr[i];
                a0+=q0[i].x*kv.x+q0[i].y*kv.y+q0[i].z*kv.z+q0[i].w*kv.w;
                a1+=q1[i].x*kv.x+q1[i].y*kv.y+q1[i].z*kv.z+q1[i].w*kv.w;
            }
            s0[j]=a0; s1[j]=a1;
            tm0=fmaxf(tm0,a0); tm1=fmaxf(tm1,a1);
        }
        float nm0=fmaxf(mx0,tm0), nm1=fmaxf(mx1,tm1);
        float c0=__expf(mx0-nm0), c1=__expf(mx1-nm1);
        sm0*=c0; sm1*=c1;
        #pragma unroll
        for (int i=0;i<5;i++){
            o0[i].x*=c0; o0[i].y*=c0; o0[i].z*=c0; o0[i].w*=c0;
            o1[i].x*=c1; o1[i].y*=c1; o1[i].z*=c1; o1[i].w*=c1;
        }
        mx0=nm0; mx1=nm1;
        #pragma unroll
        for (int j=0;j<MT;j++){
            float p0=__expf(s0[j]-nm0), p1=__expf(s1[j]-nm1);
            sm0+=p0; sm1+=p1;
            const float4* vr=(const float4*)(sv+(mt0+j)*HH);
            #pragma unroll
            for (int i=0;i<5;i++){
                float4 vv=vr[i];
                o0[i].x+=p0*vv.x; o0[i].y+=p0*vv.y; o0[i].z+=p0*vv.z; o0[i].w+=p0*vv.w;
                o1[i].x+=p1*vv.x; o1[i].y+=p1*vv.y; o1[i].z+=p1*vv.z; o1[i].w+=p1*vv.w;
            }
        }
    }
    float* pb0 = pbuf + (((size_t)(p*SS+n)*4+mc)*BB + t)*24;
    float4* w0=(float4*)pb0;
    w0[0]=make_float4(mx0,sm0,o0[0].x,o0[0].y);
    w0[1]=make_float4(o0[0].z,o0[0].w,o0[1].x,o0[1].y);
    w0[2]=make_float4(o0[1].z,o0[1].w,o0[2].x,o0[2].y);
    w0[3]=make_float4(o0[2].z,o0[2].w,o0[3].x,o0[3].y);
    w0[4]=make_float4(o0[3].z,o0[3].w,o0[4].x,o0[4].y);
    w0[5]=make_float4(o0[4].z,o0[4].w,0.f,0.f);
    float4* w1=(float4*)(pb0 + (size_t)256*24);
    w1[0]=make_float4(mx1,sm1,o1[0].x,o1[0].y);
    w1[1]=make_float4(o1[0].z,o1[0].w,o1[1].x,o1[1].y);
    w1[2]=make_float4(o1[1].z,o1[1].w,o1[2].x,o1[2].y);
    w1[3]=make_float4(o1[2].z,o1[2].w,o1[3].x,o1[3].y);
    w1[4]=make_float4(o1[3].z,o1[3].w,o1[4].x,o1[4].y);
    w1[5]=make_float4(o1[4].z,o1[4].w,0.f,0.f);
}

// merge 4 chunk-partials -> attn out -> out-proj -> residual MLP -> x[20]
__device__ __forceinline__ void merge_res(const float* __restrict__ pbase,
    const float* __restrict__ sow, const float* __restrict__ sob,
    const float* __restrict__ sw1, const float* __restrict__ sb1,
    const float* __restrict__ sw2, const float* __restrict__ sb2,
    float* __restrict__ xo)
{
    float mx=-1e30f;
    #pragma unroll
    for (int mc2=0;mc2<4;mc2++) mx=fmaxf(mx, pbase[mc2*PBSTRIDE]);
    float sum=0.f, o[HH];
    #pragma unroll
    for (int e=0;e<HH;e++) o[e]=0.f;
    #pragma unroll
    for (int mc2=0;mc2<4;mc2++){
        const float4* pc=(const float4*)(pbase+mc2*PBSTRIDE);
        float4 a=pc[0], b4=pc[1], c4=pc[2], d4=pc[3], e4=pc[4], f4=pc[5];
        float cc=__expf(a.x-mx);
        sum+=a.y*cc;
        o[0]+=a.z*cc;  o[1]+=a.w*cc;
        o[2]+=b4.x*cc; o[3]+=b4.y*cc; o[4]+=b4.z*cc; o[5]+=b4.w*cc;
        o[6]+=c4.x*cc; o[7]+=c4.y*cc; o[8]+=c4.z*cc; o[9]+=c4.w*cc;
        o[10]+=d4.x*cc; o[11]+=d4.y*cc; o[12]+=d4.z*cc; o[13]+=d4.w*cc;
        o[14]+=e4.x*cc; o[15]+=e4.y*cc; o[16]+=e4.z*cc; o[17]+=e4.w*cc;
        o[18]+=f4.x*cc; o[19]+=f4.y*cc;
    }
    float inv=frcp(sum);
    float ao[HH];
    #pragma unroll
    for (int e=0;e<HH;e++) ao[e]=o[e]*inv;
    float mo[HH];
    #pragma unroll
    for (int e=0;e<HH;e++){
        float acc=sob[e];
        #pragma unroll
        for (int f=0;f<HH;f++) acc+=sow[e*HH+f]*ao[f];
        mo[e]=acc;
    }
    float u[HH];
    #pragma unroll
    for (int g=0;g<HH;g++){
        float acc=sb1[g];
        #pragma unroll
        for (int f=0;f<HH;f++) acc+=sw1[g*HH+f]*mo[f];
        u[g]=fmaxf(acc,0.f);
    }
    #pragma unroll
    for (int e=0;e<HH;e++){
        float acc=mo[e]+sb2[e];
        #pragma unroll
        for (int g=0;g<HH;g++) acc+=sw2[e*HH+g]*u[g];
        xo[e]=acc;
    }
}

// fin (layer1) fused with layer-2 QKV. grid (100, path=2)
__global__ __launch_bounds__(256)
void k_finqkv(const float* __restrict__ pbuf,
    const float* __restrict__ ow0, const float* __restrict__ ob0,
    const float* __restrict__ w10, const float* __restrict__ b10,
    const float* __restrict__ w20, const float* __restrict__ b20,
    const float* __restrict__ iw0, const float* __restrict__ ib0,
    const float* __restrict__ ow1, const float* __restrict__ ob1,
    const float* __restrict__ w11, const float* __restrict__ b11,
    const float* __restrict__ w21, const float* __restrict__ b21,
    const float* __restrict__ iw1, const float* __restrict__ ib1,
    float* __restrict__ q_t, float* __restrict__ k_t, float* __restrict__ v_t)
{
    __shared__ float sow[400], sw1[400], sw2[400], siw[1200];
    __shared__ float sob[20], sb1[20], sb2[20], sib[60];
    const int p=blockIdx.y, t=threadIdx.x;
    const int s=blockIdx.x>>1, b=(blockIdx.x&1)*256+t;
    const float* OW=p?ow1:ow0; const float* OB=p?ob1:ob0;
    const float* W1=p?w11:w10; const float* B1=p?b11:b10;
    const float* W2=p?w21:w20; const float* B2=p?b21:b20;
    const float* IW=p?iw1:iw0; const float* IB=p?ib1:ib0;
    for (int i=t;i<400;i+=256){ sow[i]=OW[i]; sw1[i]=W1[i]; sw2[i]=W2[i]; }
    for (int i=t;i<1200;i+=256) siw[i]=IW[i];
    if (t<20){ sob[t]=OB[t]; sb1[t]=B1[t]; sb2[t]=B2[t]; }
    if (t<60) sib[t]=IB[t];
    __syncthreads();
    const float* pbase = pbuf + (((size_t)(p*SS+s)*4)*BB + b)*24;
    float xo[HH];
    merge_res(pbase, sow,sob,sw1,sb1,sw2,sb2, xo);
    const float SCALE = 0.22360679774997896f;
    size_t off0=((size_t)(p*SS+s)*BB + b)*HH;
    #pragma unroll
    for (int c=0;c<HH;c++){
        float aq=sib[c], ak=sib[20+c], av=sib[40+c];
        #pragma unroll
        for (int e=0;e<HH;e++){ float xv=xo[e]; aq+=siw[c*HH+e]*xv; ak+=siw[(20+c)*HH+e]*xv; av+=siw[(40+c)*HH+e]*xv; }
        q_t[off0+c]=aq*SCALE; k_t[off0+c]=ak; v_t[off0+c]=av;
    }
}

// final fin (layer 2): writes xout[p][b][s][e]
__global__ __launch_bounds__(256)
void k_fin(const float* __restrict__ pbuf,
    const float* __restrict__ ow0, const float* __restrict__ ob0,
    const float* __restrict__ w10, const float* __restrict__ b10,
    const float* __restrict__ w20, const float* __restrict__ b20,
    const float* __restrict__ ow1, const float* __restrict__ ob1,
    const float* __restrict__ w11, const float* __restrict__ b11,
    const float* __restrict__ w21, const float* __restrict__ b21,
    float* __restrict__ xout)
{
    __shared__ float sow[400], sw1[400], sw2[400];
    __shared__ float sob[20], sb1[20], sb2[20];
    const int p=blockIdx.y, t=threadIdx.x;
    const int s=blockIdx.x>>1, b=(blockIdx.x&1)*256+t;
    const float* OW=p?ow1:ow0; const float* OB=p?ob1:ob0;
    const float* W1=p?w11:w10; const float* B1=p?b11:b10;
    const float* W2=p?w21:w20; const float* B2=p?b21:b20;
    for (int i=t;i<400;i+=256){ sow[i]=OW[i]; sw1[i]=W1[i]; sw2[i]=W2[i]; }
    if (t<20){ sob[t]=OB[t]; sb1[t]=B1[t]; sb2[t]=B2[t]; }
    __syncthreads();
    const float* pbase = pbuf + (((size_t)(p*SS+s)*4)*BB + b)*24;
    float xo[HH];
    merge_res(pbase, sow,sob,sw1,sb1,sw2,sb2, xo);
    size_t off=((size_t)(p*BB+b)*SS + s)*HH;
    #pragma unroll
    for (int e=0;e<HH;e++) xout[off+e]=xo[e];
}

__global__ __launch_bounds__(64)
void k_head(const float* __restrict__ xout, const int* __restrict__ last,
            const float* __restrict__ ht_item, const float* __restrict__ ht_cat,
            const float* __restrict__ mem_M, const float* __restrict__ mem_Wa,
            const float* __restrict__ mem_fc,
            const float* __restrict__ wc, const float* __restrict__ bc,
            const float* __restrict__ wp, const float* __restrict__ bp,
            float* __restrict__ final_)
{
    int b=blockIdx.x*64+threadIdx.x;
    if (b>=BB) return;
    int l=last[b];
    const float* xi = xout + ((size_t)(0*BB+b)*SS + l)*HH;
    const float* xc = xout + ((size_t)(1*BB+b)*SS + l)*HH;
    float a[40];
    #pragma unroll
    for (int e=0;e<HH;e++){
        a[e]    = 0.52f*xi[e] + 0.48f*ht_item[b*HH+e];
        a[20+e] = 0.52f*xc[e] + 0.48f*ht_cat [b*HH+e];
    }
    float t20[20];
    #pragma unroll
    for (int j=0;j<20;j++){
        float acc=0.f;
        #pragma unroll
        for (int k=0;k<40;k++) acc+=a[k]*mem_Wa[k*20+j];
        t20[j]=acc;
    }
    float lg[10]; float mxv=-1e30f;
    #pragma unroll
    for (int c=0;c<10;c++){
        float acc=0.f;
        #pragma unroll
        for (int j=0;j<20;j++) acc+=t20[j]*mem_M[c*20+j];
        lg[c]=acc; mxv=fmaxf(mxv,acc);
    }
    float se=0.f;
    #pragma unroll
    for (int c=0;c<10;c++){ lg[c]=__expf(lg[c]-mxv); se+=lg[c]; }
    float inv=frcp(se);
    #pragma unroll
    for (int c=0;c<10;c++) lg[c]*=inv;
    float am[20];
    #pragma unroll
    for (int j=0;j<20;j++){
        float acc=0.f;
        #pragma unroll
        for (int c=0;c<10;c++) acc+=lg[c]*mem_M[c*20+j];
        am[j]=acc;
    }
    float reps[20];
    #pragma unroll
    for (int j2=0;j2<20;j2++){
        float acc=0.f;
        #pragma unroll
        for (int j=0;j<20;j++) acc+=am[j]*mem_fc[j*20+j2];
        reps[j2]=ftanh(acc);
    }
    #pragma unroll
    for (int e=0;e<HH;e++){
        float c1=bc[e], c2=bp[e];
        #pragma unroll
        for (int k=0;k<40;k++){ c1+=a[k]*wc[e*60+k]; c2+=a[k]*wp[e*60+k]; }
        #pragma unroll
        for (int k=0;k<20;k++){ c1+=reps[k]*wc[e*60+40+k]; c2+=reps[k]*wp[e*60+40+k]; }
        final_[b*HH+e]=fsig(c1)*c2;
    }
}

__global__ __launch_bounds__(256)
void k_scores(const float* __restrict__ final_, const float* __restrict__ emb,
              float* __restrict__ out)
{
    int node = blockIdx.x*256 + threadIdx.x;
    if (node >= NN-1) return;
    float4 er[5];
    const float4* e4 = (const float4*)(emb + ((size_t)node + 1)*HH);
    #pragma unroll
    for (int i=0;i<5;i++) er[i]=e4[i];
    float* op = out + node;
    for (int b = 0; b < BB; b++) {
        const float4* fb = (const float4*)(final_ + b*HH);
        float acc = 0.f;
        #pragma unroll
        for (int i=0;i<5;i++){
            float4 f=fb[i];
            acc += f.x*er[i].x + f.y*er[i].y + f.z*er[i].z + f.w*er[i].w;
        }
        *op = acc;
        op += (NN-1);
    }
}

extern "C" void kernel_launch(void* const* d_in, const int* in_sizes, int n_in,
                              void* d_out, int out_size, void* d_ws, size_t ws_size,
                              hipStream_t stream) {
    const int*   inputs   = (const int*)  d_in[0];
    const int*   category = (const int*)  d_in[1];
    const float* A        = (const float*)d_in[2];
    const int*   mask     = (const int*)  d_in[3];
    const float* emb      = (const float*)d_in[4];
    const float* emb1     = (const float*)d_in[5];
    const float* w_ih     = (const float*)d_in[6];
    const float* w_hh     = (const float*)d_in[7];
    const float* b_ih     = (const float*)d_in[8];
    const float* b_hh     = (const float*)d_in[9];
    const float* b_iah    = (const float*)d_in[10];
    const float* b_oah    = (const float*)d_in[11];
    const float* w_ein    = (const float*)d_in[12];
    const float* b_ein    = (const float*)d_in[13];
    const float* w_eout   = (const float*)d_in[14];
    const float* b_eout   = (const float*)d_in[15];
    const float* mha_in_w  = (const float*)d_in[16];
    const float* mha_in_b  = (const float*)d_in[17];
    const float* mha_out_w = (const float*)d_in[18];
    const float* mha_out_b = (const float*)d_in[19];
    const float* mha1_in_w  = (const float*)d_in[20];
    const float* mha1_in_b  = (const float*)d_in[21];
    const float* mha1_out_w = (const float*)d_in[22];
    const float* mha1_out_b = (const float*)d_in[23];
    const float* rn_w1 = (const float*)d_in[24];
    const float* rn_b1 = (const float*)d_in[25];
    const float* rn_w2 = (const float*)d_in[26];
    const float* rn_b2 = (const float*)d_in[27];
    const float* rn1_w1 = (const float*)d_in[28];
    const float* rn1_b1 = (const float*)d_in[29];
    const float* rn1_w2 = (const float*)d_in[30];
    const float* rn1_b2 = (const float*)d_in[31];
    const float* mem_M  = (const float*)d_in[32];
    const float* mem_Wa = (const float*)d_in[33];
    const float* mem_fc = (const float*)d_in[34];
    const float* wc = (const float*)d_in[35];
    const float* bc = (const float*)d_in[36];
    const float* wp = (const float*)d_in[37];
    const float* bp = (const float*)d_in[38];
    float* out = (float*)d_out;

    float* W = (float*)d_ws;
    float* q_t   = W;
    float* k_t   = W + 1024000;
    float* v_t   = W + 2048000;
    float* pbuf  = W + 3072000;       // 4,915,200 floats
    float* xout  = W + 7987200;       // 1,024,000
    float* ht_item = W + 9011200;
    float* ht_cat  = W + 9021440;
    float* final_  = W + 9031680;
    int*   last    = (int*)(W + 9041920);

    // 1. fused gather + GNN + last/ht + layer-1 QKV (both paths)
    k_gnnqkv<<<BB, 256, 0, stream>>>(inputs, category, A, mask, emb, emb1,
                                     w_ih, w_hh, b_ih, b_hh, b_iah, b_oah,
                                     w_ein, b_ein, w_eout, b_eout,
                                     mha_in_w, mha_in_b, mha1_in_w, mha1_in_b,
                                     q_t, k_t, v_t, last, ht_item, ht_cat);
    // 2. layer-1 attention partials (both paths)
    k_attn<<<dim3(SS,2,4), 256, 0, stream>>>(q_t, k_t, v_t, pbuf);
    // 3. layer-1 finish + layer-2 QKV
    k_finqkv<<<dim3(100,2), 256, 0, stream>>>(pbuf,
        mha_out_w, mha_out_b, rn_w1, rn_b1, rn_w2, rn_b2, mha_in_w, mha_in_b,
        mha1_out_w, mha1_out_b, rn1_w1, rn1_b1, rn1_w2, rn1_b2, mha1_in_w, mha1_in_b,
        q_t, k_t, v_t);
    // 4. layer-2 attention partials
    k_attn<<<dim3(SS,2,4), 256, 0, stream>>>(q_t, k_t, v_t, pbuf);
    // 5. layer-2 finish -> xout
    k_fin<<<dim3(100,2), 256, 0, stream>>>(pbuf,
        mha_out_w, mha_out_b, rn_w1, rn_b1, rn_w2, rn_b2,
        mha1_out_w, mha1_out_b, rn1_w1, rn1_b1, rn1_w2, rn1_b2,
        xout);
    // 6. memory readout + heads
    k_head<<<8, 64, 0, stream>>>(xout, last, ht_item, ht_cat,
                                 mem_M, mem_Wa, mem_fc, wc, bc, wp, bp, final_);
    // 7. scores = final @ emb[1:].T
    k_scores<<<(NN-1+255)/256, 256, 0, stream>>>(final_, emb, out);
}

// Round 3
// 582.669 us; speedup vs baseline: 1.4889x; 1.1260x over previous
//
#include <hip/hip_runtime.h>
#include <hip/hip_bf16.h>

#define BB 512
#define SS 50
#define HH 20
#define NN 100000
#define NMC 8          // m-chunks per attention
#define MCH 64         // m-chunk size
#define NRC 4          // row-chunks per attention
#define MT 16          // m register tile
#define PBSTRIDE ((size_t)BB*24)

__device__ __forceinline__ float frcp(float x){
#if __has_builtin(__builtin_amdgcn_rcpf)
  return __builtin_amdgcn_rcpf(x);
#else
  return 1.f/x;
#endif
}
__device__ __forceinline__ float fsig(float x){ return frcp(1.f + __expf(-x)); }
__device__ __forceinline__ float ftanh(float x){ return 1.f - 2.f*frcp(1.f + __expf(2.f*x)); }

// ------------------------------------------------------------------
// Fused: embedding gather + edge proj + GNN cell + last/ht snapshot +
// layer-1 QKV for BOTH paths. One block per session b.
// ------------------------------------------------------------------
__global__ __launch_bounds__(256)
void k_gnnqkv(const int* __restrict__ inputs, const int* __restrict__ category,
              const float* __restrict__ A, const int* __restrict__ mask,
              const float* __restrict__ emb, const float* __restrict__ emb1,
              const float* __restrict__ w_ih, const float* __restrict__ w_hh,
              const float* __restrict__ b_ih, const float* __restrict__ b_hh,
              const float* __restrict__ b_iah, const float* __restrict__ b_oah,
              const float* __restrict__ w_ein, const float* __restrict__ b_ein,
              const float* __restrict__ w_eout, const float* __restrict__ b_eout,
              const float* __restrict__ inw0, const float* __restrict__ inb0,
              const float* __restrict__ inw1, const float* __restrict__ inb1,
              float* __restrict__ q_t, float* __restrict__ k_t, float* __restrict__ v_t,
              int* __restrict__ last, float* __restrict__ ht_item, float* __restrict__ ht_cat)
{
    __shared__ float sA[SS*2*SS];
    __shared__ float sit[SS*HH], sct[SS*HH], shin[SS*HH], shout[SS*HH];
    __shared__ float sinp[SS*HH], soutp[SS*HH];
    __shared__ float swein[HH*HH], sweout[HH*HH];
    __shared__ float swih[60*40], swhh[60*HH];
    __shared__ float sw0[60*HH], sw1w[60*HH];
    __shared__ float sbein[HH], sbeout[HH], sbih[60], sbhh[60], sbiah[HH], sboah[HH], sb0[60], sb1b[60];
    __shared__ int slast;
    const int b = blockIdx.x, t = threadIdx.x;

    for (int i=t;i<SS*2*SS;i+=256) sA[i] = A[(size_t)b*SS*2*SS + i];
    for (int i=t;i<HH*HH;i+=256) { swein[i]=w_ein[i]; sweout[i]=w_eout[i]; }
    for (int i=t;i<60*40;i+=256) swih[i]=w_ih[i];
    for (int i=t;i<60*HH;i+=256) { swhh[i]=w_hh[i]; sw0[i]=inw0[i]; sw1w[i]=inw1[i]; }
    if (t<60){ sbih[t]=b_ih[t]; sbhh[t]=b_hh[t]; sb0[t]=inb0[t]; sb1b[t]=inb1[t]; }
    if (t<HH){ sbein[t]=b_ein[t]; sbeout[t]=b_eout[t]; sbiah[t]=b_iah[t]; sboah[t]=b_oah[t]; }
    for (int i=t;i<SS*HH;i+=256){
        int r=i/HH, e=i%HH;
        sit[i]=emb [(size_t)inputs  [b*SS+r]*HH+e];
        sct[i]=emb1[(size_t)category[b*SS+r]*HH+e];
    }
    if (t==0){ int s=0; for (int j=0;j<SS;j++) s+=mask[b*SS+j]; slast=s-1; }
    __syncthreads();

    for (int i=t;i<SS*HH;i+=256){
        int r=i/HH, c=i%HH;
        float si=sbein[c], so=sbeout[c];
        #pragma unroll
        for (int e=0;e<HH;e++){ float hv=sit[r*HH+e]; si+=swein[c*HH+e]*hv; so+=sweout[c*HH+e]*hv; }
        shin[i]=si; shout[i]=so;
    }
    __syncthreads();
    for (int i=t;i<SS*HH;i+=256){
        int r=i/HH, e=i%HH;
        float ai=sbiah[e], ao=sboah[e];
        #pragma unroll 5
        for (int j=0;j<SS;j++){
            ai+=sA[r*2*SS+j]   *shin [j*HH+e];
            ao+=sA[r*2*SS+SS+j]*shout[j*HH+e];
        }
        sinp[i]=ai; soutp[i]=ao;
    }
    __syncthreads();
    float nh[4];
    #pragma unroll
    for (int ii=0;ii<4;ii++){
        int i=t+ii*256;
        if (i<SS*HH){
            int r=i/HH, e=i%HH;
            float gir=sbih[e], gii=sbih[20+e], gin=sbih[40+e];
            #pragma unroll
            for (int k=0;k<HH;k++){
                float vi=sinp[r*HH+k], vo=soutp[r*HH+k];
                gir+=swih[e*40+k]*vi      + swih[e*40+HH+k]*vo;
                gii+=swih[(20+e)*40+k]*vi + swih[(20+e)*40+HH+k]*vo;
                gin+=swih[(40+e)*40+k]*vi + swih[(40+e)*40+HH+k]*vo;
            }
            float ghr=sbhh[e], ghi=sbhh[20+e], ghn=sbhh[40+e];
            #pragma unroll
            for (int k=0;k<HH;k++){
                float hv=sit[r*HH+k];
                ghr+=swhh[e*HH+k]*hv; ghi+=swhh[(20+e)*HH+k]*hv; ghn+=swhh[(40+e)*HH+k]*hv;
            }
            float rr=fsig(gir+ghr), zz=fsig(gii+ghi);
            float nn2=ftanh(gin+rr*ghn);
            nh[ii]=nn2+zz*(sit[i]-nn2);
        }
    }
    __syncthreads();
    #pragma unroll
    for (int ii=0;ii<4;ii++){ int i=t+ii*256; if (i<SS*HH) sit[i]=nh[ii]; }
    __syncthreads();

    if (t<HH)                    ht_item[b*HH+t]      = sit[slast*HH+t];
    else if (t>=32 && t<32+HH)   ht_cat [b*HH+(t-32)] = sct[slast*HH+(t-32)];
    else if (t==63)              last[b]=slast;

    const float SCALE = 0.22360679774997896f;
    for (int oi=t; oi<2*SS*60; oi+=256){
        int p=oi/(SS*60); int rem=oi%(SS*60); int r=rem/60; int c=rem%60;
        const float* src = p? sct  : sit;
        const float* w   = p? sw1w : sw0;
        const float* bb_ = p? sb1b : sb0;
        float acc=bb_[c];
        #pragma unroll
        for (int e=0;e<HH;e++) acc += w[c*HH+e]*src[r*HH+e];
        int which=c/HH, cc=c%HH;
        size_t off=((size_t)(p*SS+r)*BB + b)*HH + cc;
        if (which==0)      q_t[off]=acc*SCALE;
        else if (which==1) k_t[off]=acc;
        else               v_t[off]=acc;
    }
}

// needed[s] = any(last[b]==s)
__global__ __launch_bounds__(256)
void k_flags(const int* __restrict__ last, int* __restrict__ needed)
{
    __shared__ int nf[SS];
    int t=threadIdx.x;
    if (t<SS) nf[t]=0;
    __syncthreads();
    for (int b=t;b<BB;b+=256){ int l=last[b]; atomicOr(&nf[l],1); }
    __syncthreads();
    if (t<SS) needed[t]=nf[t];
}

// ------------------------------------------------------------------
// Gated attention partials. grid (s=50, p=2, z=32: mc=z>>2, rc=z&3),
// 128 threads, 1 row/thread, m-chunk of 64, flash online softmax.
// ------------------------------------------------------------------
__global__ __launch_bounds__(128)
void k_attn(const float* __restrict__ q_t, const float* __restrict__ k_t,
            const float* __restrict__ v_t, const int* __restrict__ needed,
            float* __restrict__ pbuf)
{
    const int s=blockIdx.x, p=blockIdx.y, z=blockIdx.z;
    if (!needed[s]) return;
    const int mc=z>>2, rc=z&3, t=threadIdx.x;
    __shared__ float sk[MCH*HH], sv[MCH*HH];
    const size_t base=(size_t)(p*SS+s)*BB;
    {
        const float4* kb=(const float4*)(k_t+(base+(size_t)mc*MCH)*HH);
        const float4* vb=(const float4*)(v_t+(base+(size_t)mc*MCH)*HH);
        float4* sk4=(float4*)sk; float4* sv4=(float4*)sv;
        for (int i=t;i<MCH*HH/4;i+=128){ sk4[i]=kb[i]; sv4[i]=vb[i]; }
    }
    __syncthreads();
    const int row = rc*128 + t;
    float4 q[5];
    {
        const float4* qp=(const float4*)(q_t+(base+row)*HH);
        #pragma unroll
        for (int i=0;i<5;i++) q[i]=qp[i];
    }
    float4 o[5];
    #pragma unroll
    for (int i=0;i<5;i++) o[i]=make_float4(0.f,0.f,0.f,0.f);
    float mx=-1e30f, sm=0.f;

    for (int mt0=0; mt0<MCH; mt0+=MT){
        float sc[MT]; float tm=-1e30f;
        #pragma unroll
        for (int j=0;j<MT;j++){
            const float4* kr=(const float4*)(sk+(mt0+j)*HH);
            float a0=0.f;
            #pragma unroll
            for (int i=0;i<5;i++){
                float4 kv=kr[i];
                a0+=q[i].x*kv.x+q[i].y*kv.y+q[i].z*kv.z+q[i].w*kv.w;
            }
            sc[j]=a0; tm=fmaxf(tm,a0);
        }
        float nm=fmaxf(mx,tm);
        float c=__expf(mx-nm);
        sm*=c;
        #pragma unroll
        for (int i=0;i<5;i++){ o[i].x*=c; o[i].y*=c; o[i].z*=c; o[i].w*=c; }
        mx=nm;
        #pragma unroll
        for (int j=0;j<MT;j++){
            float pe=__expf(sc[j]-nm);
            sm+=pe;
            const float4* vr=(const float4*)(sv+(mt0+j)*HH);
            #pragma unroll
            for (int i=0;i<5;i++){
                float4 vv=vr[i];
                o[i].x+=pe*vv.x; o[i].y+=pe*vv.y; o[i].z+=pe*vv.z; o[i].w+=pe*vv.w;
            }
        }
    }
    float* pb = pbuf + (((size_t)(p*SS+s)*NMC+mc)*BB + row)*24;
    float4* w0=(float4*)pb;
    w0[0]=make_float4(mx,sm,o[0].x,o[0].y);
    w0[1]=make_float4(o[0].z,o[0].w,o[1].x,o[1].y);
    w0[2]=make_float4(o[1].z,o[1].w,o[2].x,o[2].y);
    w0[3]=make_float4(o[2].z,o[2].w,o[3].x,o[3].y);
    w0[4]=make_float4(o[3].z,o[3].w,o[4].x,o[4].y);
    w0[5]=make_float4(o[4].z,o[4].w,0.f,0.f);
}

// merge NMC chunk-partials -> attn out -> out-proj -> residual MLP -> x[20]
__device__ __forceinline__ void merge_res(const float* __restrict__ pbase,
    const float* __restrict__ sow, const float* __restrict__ sob,
    const float* __restrict__ sw1, const float* __restrict__ sb1,
    const float* __restrict__ sw2, const float* __restrict__ sb2,
    float* __restrict__ xo)
{
    float mx=-1e30f;
    #pragma unroll
    for (int mc2=0;mc2<NMC;mc2++) mx=fmaxf(mx, pbase[mc2*PBSTRIDE]);
    float sum=0.f, o[HH];
    #pragma unroll
    for (int e=0;e<HH;e++) o[e]=0.f;
    #pragma unroll
    for (int mc2=0;mc2<NMC;mc2++){
        const float4* pc=(const float4*)(pbase+mc2*PBSTRIDE);
        float4 a=pc[0], b4=pc[1], c4=pc[2], d4=pc[3], e4=pc[4], f4=pc[5];
        float cc=__expf(a.x-mx);
        sum+=a.y*cc;
        o[0]+=a.z*cc;  o[1]+=a.w*cc;
        o[2]+=b4.x*cc; o[3]+=b4.y*cc; o[4]+=b4.z*cc; o[5]+=b4.w*cc;
        o[6]+=c4.x*cc; o[7]+=c4.y*cc; o[8]+=c4.z*cc; o[9]+=c4.w*cc;
        o[10]+=d4.x*cc; o[11]+=d4.y*cc; o[12]+=d4.z*cc; o[13]+=d4.w*cc;
        o[14]+=e4.x*cc; o[15]+=e4.y*cc; o[16]+=e4.z*cc; o[17]+=e4.w*cc;
        o[18]+=f4.x*cc; o[19]+=f4.y*cc;
    }
    float inv=frcp(sum);
    float ao[HH];
    #pragma unroll
    for (int e=0;e<HH;e++) ao[e]=o[e]*inv;
    float mo[HH];
    #pragma unroll
    for (int e=0;e<HH;e++){
        float acc=sob[e];
        #pragma unroll
        for (int f=0;f<HH;f++) acc+=sow[e*HH+f]*ao[f];
        mo[e]=acc;
    }
    float u[HH];
    #pragma unroll
    for (int g=0;g<HH;g++){
        float acc=sb1[g];
        #pragma unroll
        for (int f=0;f<HH;f++) acc+=sw1[g*HH+f]*mo[f];
        u[g]=fmaxf(acc,0.f);
    }
    #pragma unroll
    for (int e=0;e<HH;e++){
        float acc=mo[e]+sb2[e];
        #pragma unroll
        for (int g=0;g<HH;g++) acc+=sw2[e*HH+g]*u[g];
        xo[e]=acc;
    }
}

// layer-1 finish + layer-2 QKV. grid (100, 2), gated by needed[s]
__global__ __launch_bounds__(256)
void k_finqkv(const float* __restrict__ pbuf, const int* __restrict__ needed,
    const float* __restrict__ ow0, const float* __restrict__ ob0,
    const float* __restrict__ w10, const float* __restrict__ b10,
    const float* __restrict__ w20, const float* __restrict__ b20,
    const float* __restrict__ iw0, const float* __restrict__ ib0,
    const float* __restrict__ ow1, const float* __restrict__ ob1,
    const float* __restrict__ w11, const float* __restrict__ b11,
    const float* __restrict__ w21, const float* __restrict__ b21,
    const float* __restrict__ iw1, const float* __restrict__ ib1,
    float* __restrict__ q_t, float* __restrict__ k_t, float* __restrict__ v_t)
{
    const int s=blockIdx.x>>1;
    if (!needed[s]) return;
    __shared__ float sow[400], sw1[400], sw2[400], siw[1200];
    __shared__ float sob[20], sb1[20], sb2[20], sib[60];
    const int p=blockIdx.y, t=threadIdx.x;
    const int b=(blockIdx.x&1)*256+t;
    const float* OW=p?ow1:ow0; const float* OB=p?ob1:ob0;
    const float* W1=p?w11:w10; const float* B1=p?b11:b10;
    const float* W2=p?w21:w20; const float* B2=p?b21:b20;
    const float* IW=p?iw1:iw0; const float* IB=p?ib1:ib0;
    for (int i=t;i<400;i+=256){ sow[i]=OW[i]; sw1[i]=W1[i]; sw2[i]=W2[i]; }
    for (int i=t;i<1200;i+=256) siw[i]=IW[i];
    if (t<20){ sob[t]=OB[t]; sb1[t]=B1[t]; sb2[t]=B2[t]; }
    if (t<60) sib[t]=IB[t];
    __syncthreads();
    const float* pbase = pbuf + (((size_t)(p*SS+s)*NMC)*BB + b)*24;
    float xo[HH];
    merge_res(pbase, sow,sob,sw1,sb1,sw2,sb2, xo);
    const float SCALE = 0.22360679774997896f;
    size_t off0=((size_t)(p*SS+s)*BB + b)*HH;
    #pragma unroll
    for (int c=0;c<HH;c++){
        float aq=sib[c], ak=sib[20+c], av=sib[40+c];
        #pragma unroll
        for (int e=0;e<HH;e++){ float xv=xo[e]; aq+=siw[c*HH+e]*xv; ak+=siw[(20+c)*HH+e]*xv; av+=siw[(40+c)*HH+e]*xv; }
        q_t[off0+c]=aq*SCALE; k_t[off0+c]=ak; v_t[off0+c]=av;
    }
}

// layer-2 finish fused with a = 0.52*x + 0.48*ht, only for rows s==last[b]
__global__ __launch_bounds__(256)
void k_fin(const float* __restrict__ pbuf, const int* __restrict__ needed,
    const int* __restrict__ last,
    const float* __restrict__ ht_item, const float* __restrict__ ht_cat,
    const float* __restrict__ ow0, const float* __restrict__ ob0,
    const float* __restrict__ w10, const float* __restrict__ b10,
    const float* __restrict__ w20, const float* __restrict__ b20,
    const float* __restrict__ ow1, const float* __restrict__ ob1,
    const float* __restrict__ w11, const float* __restrict__ b11,
    const float* __restrict__ w21, const float* __restrict__ b21,
    float* __restrict__ a_out)
{
    const int s=blockIdx.x>>1;
    if (!needed[s]) return;
    __shared__ float sow[400], sw1[400], sw2[400];
    __shared__ float sob[20], sb1[20], sb2[20];
    const int p=blockIdx.y, t=threadIdx.x;
    const int b=(blockIdx.x&1)*256+t;
    const float* OW=p?ow1:ow0; const float* OB=p?ob1:ob0;
    const float* W1=p?w11:w10; const float* B1=p?b11:b10;
    const float* W2=p?w21:w20; const float* B2=p?b21:b20;
    for (int i=t;i<400;i+=256){ sow[i]=OW[i]; sw1[i]=W1[i]; sw2[i]=W2[i]; }
    if (t<20){ sob[t]=OB[t]; sb1[t]=B1[t]; sb2[t]=B2[t]; }
    __syncthreads();
    if (last[b] != s) return;
    const float* pbase = pbuf + (((size_t)(p*SS+s)*NMC)*BB + b)*24;
    float xo[HH];
    merge_res(pbase, sow,sob,sw1,sb1,sw2,sb2, xo);
    const float* ht = p? ht_cat : ht_item;
    #pragma unroll
    for (int e=0;e<HH;e++)
        a_out[(size_t)b*40 + p*HH + e] = 0.52f*xo[e] + 0.48f*ht[b*HH+e];
}

__global__ __launch_bounds__(64)
void k_head(const float* __restrict__ a_in,
            const float* __restrict__ mem_M, const float* __restrict__ mem_Wa,
            const float* __restrict__ mem_fc,
            const float* __restrict__ wc, const float* __restrict__ bc,
            const float* __restrict__ wp, const float* __restrict__ bp,
            float* __restrict__ final_)
{
    int b=blockIdx.x*64+threadIdx.x;
    if (b>=BB) return;
    float a[40];
    const float4* a4=(const float4*)(a_in+(size_t)b*40);
    #pragma unroll
    for (int i=0;i<10;i++){ float4 v=a4[i]; a[4*i]=v.x; a[4*i+1]=v.y; a[4*i+2]=v.z; a[4*i+3]=v.w; }
    float t20[20];
    #pragma unroll
    for (int j=0;j<20;j++){
        float acc=0.f;
        #pragma unroll
        for (int k=0;k<40;k++) acc+=a[k]*mem_Wa[k*20+j];
        t20[j]=acc;
    }
    float lg[10]; float mxv=-1e30f;
    #pragma unroll
    for (int c=0;c<10;c++){
        float acc=0.f;
        #pragma unroll
        for (int j=0;j<20;j++) acc+=t20[j]*mem_M[c*20+j];
        lg[c]=acc; mxv=fmaxf(mxv,acc);
    }
    float se=0.f;
    #pragma unroll
    for (int c=0;c<10;c++){ lg[c]=__expf(lg[c]-mxv); se+=lg[c]; }
    float inv=frcp(se);
    #pragma unroll
    for (int c=0;c<10;c++) lg[c]*=inv;
    float am[20];
    #pragma unroll
    for (int j=0;j<20;j++){
        float acc=0.f;
        #pragma unroll
        for (int c=0;c<10;c++) acc+=lg[c]*mem_M[c*20+j];
        am[j]=acc;
    }
    float reps[20];
    #pragma unroll
    for (int j2=0;j2<20;j2++){
        float acc=0.f;
        #pragma unroll
        for (int j=0;j<20;j++) acc+=am[j]*mem_fc[j*20+j2];
        reps[j2]=ftanh(acc);
    }
    #pragma unroll
    for (int e=0;e<HH;e++){
        float c1=bc[e], c2=bp[e];
        #pragma unroll
        for (int k=0;k<40;k++){ c1+=a[k]*wc[e*60+k]; c2+=a[k]*wp[e*60+k]; }
        #pragma unroll
        for (int k=0;k<20;k++){ c1+=reps[k]*wc[e*60+40+k]; c2+=reps[k]*wp[e*60+40+k]; }
        final_[b*HH+e]=fsig(c1)*c2;
    }
}

__global__ __launch_bounds__(256)
void k_scores(const float* __restrict__ final_, const float* __restrict__ emb,
              float* __restrict__ out)
{
    int node = blockIdx.x*256 + threadIdx.x;
    if (node >= NN-1) return;
    float4 er[5];
    const float4* e4 = (const float4*)(emb + ((size_t)node + 1)*HH);
    #pragma unroll
    for (int i=0;i<5;i++) er[i]=e4[i];
    float* op = out + node;
    for (int b = 0; b < BB; b++) {
        const float4* fb = (const float4*)(final_ + b*HH);
        float acc = 0.f;
        #pragma unroll
        for (int i=0;i<5;i++){
            float4 f=fb[i];
            acc += f.x*er[i].x + f.y*er[i].y + f.z*er[i].z + f.w*er[i].w;
        }
        *op = acc;
        op += (NN-1);
    }
}

extern "C" void kernel_launch(void* const* d_in, const int* in_sizes, int n_in,
                              void* d_out, int out_size, void* d_ws, size_t ws_size,
                              hipStream_t stream) {
    const int*   inputs   = (const int*)  d_in[0];
    const int*   category = (const int*)  d_in[1];
    const float* A        = (const float*)d_in[2];
    const int*   mask     = (const int*)  d_in[3];
    const float* emb      = (const float*)d_in[4];
    const float* emb1     = (const float*)d_in[5];
    const float* w_ih     = (const float*)d_in[6];
    const float* w_hh     = (const float*)d_in[7];
    const float* b_ih     = (const float*)d_in[8];
    const float* b_hh     = (const float*)d_in[9];
    const float* b_iah    = (const float*)d_in[10];
    const float* b_oah    = (const float*)d_in[11];
    const float* w_ein    = (const float*)d_in[12];
    const float* b_ein    = (const float*)d_in[13];
    const float* w_eout   = (const float*)d_in[14];
    const float* b_eout   = (const float*)d_in[15];
    const float* mha_in_w  = (const float*)d_in[16];
    const float* mha_in_b  = (const float*)d_in[17];
    const float* mha_out_w = (const float*)d_in[18];
    const float* mha_out_b = (const float*)d_in[19];
    const float* mha1_in_w  = (const float*)d_in[20];
    const float* mha1_in_b  = (const float*)d_in[21];
    const float* mha1_out_w = (const float*)d_in[22];
    const float* mha1_out_b = (const float*)d_in[23];
    const float* rn_w1 = (const float*)d_in[24];
    const float* rn_b1 = (const float*)d_in[25];
    const float* rn_w2 = (const float*)d_in[26];
    const float* rn_b2 = (const float*)d_in[27];
    const float* rn1_w1 = (const float*)d_in[28];
    const float* rn1_b1 = (const float*)d_in[29];
    const float* rn1_w2 = (const float*)d_in[30];
    const float* rn1_b2 = (const float*)d_in[31];
    const float* mem_M  = (const float*)d_in[32];
    const float* mem_Wa = (const float*)d_in[33];
    const float* mem_fc = (const float*)d_in[34];
    const float* wc = (const float*)d_in[35];
    const float* bc = (const float*)d_in[36];
    const float* wp = (const float*)d_in[37];
    const float* bp = (const float*)d_in[38];
    float* out = (float*)d_out;

    float* W = (float*)d_ws;
    float* q_t     = W;                    // 1,024,000
    float* k_t     = W + 1024000;          // 1,024,000
    float* v_t     = W + 2048000;          // 1,024,000
    float* pbuf    = W + 3072000;          // 2*50*8*512*24 = 9,830,400
    float* ht_item = W + 12902400;         // 10,240
    float* ht_cat  = W + 12912640;         // 10,240
    float* a_buf   = W + 12922880;         // 20,480
    float* final_  = W + 12943360;         // 10,240
    int*   last    = (int*)(W + 12953600); // 512
    int*   needed  = (int*)(W + 12954112); // 50

    // 1. fused gather + GNN + last/ht + layer-1 QKV (both paths)
    k_gnnqkv<<<BB, 256, 0, stream>>>(inputs, category, A, mask, emb, emb1,
                                     w_ih, w_hh, b_ih, b_hh, b_iah, b_oah,
                                     w_ein, b_ein, w_eout, b_eout,
                                     mha_in_w, mha_in_b, mha1_in_w, mha1_in_b,
                                     q_t, k_t, v_t, last, ht_item, ht_cat);
    // 2. needed-s flags
    k_flags<<<1, 256, 0, stream>>>(last, needed);
    // 3. layer-1 attention partials (gated)
    k_attn<<<dim3(SS,2,NMC*NRC), 128, 0, stream>>>(q_t, k_t, v_t, needed, pbuf);
    // 4. layer-1 finish + layer-2 QKV (gated)
    k_finqkv<<<dim3(100,2), 256, 0, stream>>>(pbuf, needed,
        mha_out_w, mha_out_b, rn_w1, rn_b1, rn_w2, rn_b2, mha_in_w, mha_in_b,
        mha1_out_w, mha1_out_b, rn1_w1, rn1_b1, rn1_w2, rn1_b2, mha1_in_w, mha1_in_b,
        q_t, k_t, v_t);
    // 5. layer-2 attention partials (gated)
    k_attn<<<dim3(SS,2,NMC*NRC), 128, 0, stream>>>(q_t, k_t, v_t, needed, pbuf);
    // 6. layer-2 finish + a-mix (gated, only rows s==last[b])
    k_fin<<<dim3(100,2), 256, 0, stream>>>(pbuf, needed, last, ht_item, ht_cat,
        mha_out_w, mha_out_b, rn_w1, rn_b1, rn_w2, rn_b2,
        mha1_out_w, mha1_out_b, rn1_w1, rn1_b1, rn1_w2, rn1_b2,
        a_buf);
    // 7. memory readout + heads
    k_head<<<8, 64, 0, stream>>>(a_buf, mem_M, mem_Wa, mem_fc, wc, bc, wp, bp, final_);
    // 8. scores = final @ emb[1:].T
    k_scores<<<(NN-1+255)/256, 256, 0, stream>>>(final_, emb, out);
}